// Round 1
// baseline (228.124 us; speedup 1.0000x reference)
//
#include <hip/hip_runtime.h>
#include <hip/hip_bf16.h>
#include <math.h>

// ---------------- problem constants ----------------
#define BATCH 8
#define SEQ   2048
#define ROWS  (BATCH*SEQ)     // 16384
#define DM    1024
#define DS    64
#define NUSE  928             // 512+256+128+32 (KNOW slice unused)

// slice boundaries: [0,512) [512,768) [768,896) [896,928)
// top-k: 64, 32, sparsify 16, sparsify 3

// ---------------- workspace layout (floats) ----------------
#define OFF_ENT 0LL
#define OFF_H   (OFF_ENT + 64LL*NUSE)               // 59392
#define OFF_P   (OFF_H   + (long long)ROWS*DS)      // + 1048576
#define OFF_Z   (OFF_P   + (long long)ROWS*NUSE)    // + 15204352
#define OFF_CF  (OFF_Z   + (long long)ROWS*4)
#define OFF_WP  (OFF_CF  + (long long)ROWS*4)
// total = OFF_WP + 16*8*928 = 16,562,176 floats = 66.25 MB

// ---------------- kernel 0: normalize + transpose emb ----------------
__global__ __launch_bounds__(256) void k_prep(const float* __restrict__ emb,
                                              float* __restrict__ EnT) {
    int n = blockIdx.x * 256 + threadIdx.x;
    if (n >= NUSE) return;
    float ss = 0.f;
    #pragma unroll
    for (int d = 0; d < DS; d++) {
        float v = emb[n * DS + d];
        ss = fmaf(v, v, ss);
    }
    float inv = 1.0f / sqrtf(ss);
    #pragma unroll
    for (int d = 0; d < DS; d++) {
        EnT[(long long)d * NUSE + n] = emb[n * DS + d] * inv;
    }
}

// ---------------- kernel A: h = x@W + b  (64-row x 64-col tile per block) ----------------
__global__ __launch_bounds__(256) void k_hmm(const float* __restrict__ x,
                                             const float* __restrict__ W,
                                             const float* __restrict__ bias,
                                             float* __restrict__ h) {
    __shared__ float xT[64][68];   // [kk][row], pad->68 keeps float4 alignment (272B)
    __shared__ float wT[64][68];   // [kk][col]
    const int tid = threadIdx.x;
    const int tr = tid >> 4, tc = tid & 15;
    const long long row0 = (long long)blockIdx.x * 64;

    float acc[4][4];
    #pragma unroll
    for (int i = 0; i < 4; i++)
        #pragma unroll
        for (int j = 0; j < 4; j++) acc[i][j] = 0.f;

    for (int k0 = 0; k0 < DM; k0 += 64) {
        // stage x tile (transposed write)
        #pragma unroll
        for (int i = 0; i < 4; i++) {
            int idx = i * 256 + tid;
            int r = idx >> 4, kc = idx & 15;
            const float4 v = *(const float4*)&x[(row0 + r) * DM + k0 + kc * 4];
            xT[kc * 4 + 0][r] = v.x;
            xT[kc * 4 + 1][r] = v.y;
            xT[kc * 4 + 2][r] = v.z;
            xT[kc * 4 + 3][r] = v.w;
        }
        // stage W tile (natural layout)
        #pragma unroll
        for (int i = 0; i < 4; i++) {
            int idx = i * 256 + tid;
            int kk = idx >> 4, c4 = idx & 15;
            *(float4*)&wT[kk][c4 * 4] = *(const float4*)&W[(k0 + kk) * DS + c4 * 4];
        }
        __syncthreads();
        #pragma unroll 8
        for (int kk = 0; kk < 64; kk++) {
            const float4 a4 = *(const float4*)&xT[kk][tr * 4];
            const float4 b4 = *(const float4*)&wT[kk][tc * 4];
            const float av[4] = {a4.x, a4.y, a4.z, a4.w};
            const float bv[4] = {b4.x, b4.y, b4.z, b4.w};
            #pragma unroll
            for (int i = 0; i < 4; i++)
                #pragma unroll
                for (int j = 0; j < 4; j++)
                    acc[i][j] = fmaf(av[i], bv[j], acc[i][j]);
        }
        __syncthreads();
    }
    #pragma unroll
    for (int i = 0; i < 4; i++) {
        long long r = row0 + tr * 4 + i;
        float4 o;
        o.x = acc[i][0] + bias[tc * 4 + 0];
        o.y = acc[i][1] + bias[tc * 4 + 1];
        o.z = acc[i][2] + bias[tc * 4 + 2];
        o.w = acc[i][3] + bias[tc * 4 + 3];
        *(float4*)&h[r * DS + tc * 4] = o;
    }
}

// ---------------- kernel B1: P = exp(h @ EnT), Z slice sums ----------------
// grid: (256 row-chunks, 15 n-tiles). n-tile -> slice: 0-7 ->0, 8-11 ->1, 12-13 ->2, 14 ->3 (cols >=928 masked)
__global__ __launch_bounds__(256) void k_logits(const float* __restrict__ h,
                                                const float* __restrict__ EnT,
                                                float* __restrict__ P,
                                                float* __restrict__ Z) {
    __shared__ float hT[64][68];    // [d][row]
    __shared__ float eT[64][68];    // [d][n]
    __shared__ float zred[64][17];
    const int tid = threadIdx.x;
    const int tr = tid >> 4, tc = tid & 15;
    const long long row0 = (long long)blockIdx.x * 64;
    const int n0 = blockIdx.y * 64;

    // stage h tile (transposed)
    #pragma unroll
    for (int i = 0; i < 4; i++) {
        int idx = i * 256 + tid;
        int r = idx >> 4, dc = idx & 15;
        const float4 v = *(const float4*)&h[(row0 + r) * DS + dc * 4];
        hT[dc * 4 + 0][r] = v.x;
        hT[dc * 4 + 1][r] = v.y;
        hT[dc * 4 + 2][r] = v.z;
        hT[dc * 4 + 3][r] = v.w;
    }
    // stage e tile (EnT pre-transposed: contiguous copy, zero-fill OOB)
    #pragma unroll
    for (int i = 0; i < 4; i++) {
        int idx = i * 256 + tid;
        int d = idx >> 4, nc = idx & 15;
        int n = n0 + nc * 4;
        float4 v;
        if (n < NUSE) v = *(const float4*)&EnT[(long long)d * NUSE + n];
        else { v.x = 0.f; v.y = 0.f; v.z = 0.f; v.w = 0.f; }
        *(float4*)&eT[d][nc * 4] = v;
    }
    __syncthreads();

    float acc[4][4];
    #pragma unroll
    for (int i = 0; i < 4; i++)
        #pragma unroll
        for (int j = 0; j < 4; j++) acc[i][j] = 0.f;

    #pragma unroll 8
    for (int kk = 0; kk < 64; kk++) {
        const float4 a4 = *(const float4*)&hT[kk][tr * 4];
        const float4 b4 = *(const float4*)&eT[kk][tc * 4];
        const float av[4] = {a4.x, a4.y, a4.z, a4.w};
        const float bv[4] = {b4.x, b4.y, b4.z, b4.w};
        #pragma unroll
        for (int i = 0; i < 4; i++)
            #pragma unroll
            for (int j = 0; j < 4; j++)
                acc[i][j] = fmaf(av[i], bv[j], acc[i][j]);
    }

    const int ty = blockIdx.y;
    const int sl = (ty < 8) ? 0 : (ty < 12) ? 1 : (ty < 14) ? 2 : 3;
    const bool valid = (n0 + tc * 4) < NUSE;   // whole float4 valid or not (tile 14: tc<8)

    float rowsum[4];
    #pragma unroll
    for (int i = 0; i < 4; i++) {
        float e0 = __expf(acc[i][0]);
        float e1 = __expf(acc[i][1]);
        float e2 = __expf(acc[i][2]);
        float e3 = __expf(acc[i][3]);
        float s = 0.f;
        if (valid) {
            long long r = row0 + tr * 4 + i;
            float4 o; o.x = e0; o.y = e1; o.z = e2; o.w = e3;
            *(float4*)&P[r * NUSE + n0 + tc * 4] = o;
            s = (e0 + e1) + (e2 + e3);
        }
        rowsum[i] = s;
    }
    #pragma unroll
    for (int i = 0; i < 4; i++) zred[tr * 4 + i][tc] = rowsum[i];
    __syncthreads();
    if (tid < 64) {
        float s = 0.f;
        #pragma unroll
        for (int q = 0; q < 16; q++) s += zred[tid][q];
        atomicAdd(&Z[(row0 + tid) * 4 + sl], s);
    }
}

// ---------------- kernel Bc: coef = importance / Z ----------------
__global__ __launch_bounds__(256) void k_coef(const float* __restrict__ imp,
                                              const float* __restrict__ Z,
                                              float* __restrict__ coef) {
    int g = blockIdx.x * 256 + threadIdx.x;   // 0..16383
    float w = imp[g];
    float4 z = *(const float4*)&Z[(long long)g * 4];
    float4 c;
    c.x = w / z.x; c.y = w / z.y; c.z = w / z.z; c.w = w / z.w;
    *(float4*)&coef[(long long)g * 4] = c;
}

// ---------------- kernel B2: w partials = sum_s coef * P ----------------
// grid 512: b(8) x nchunk(8 of 128 cols) x schunk(8 of 256 rows); 256 thr: 128 cols x 2 halves
__global__ __launch_bounds__(256) void k_wacc(const float* __restrict__ P,
                                              const float* __restrict__ coef,
                                              float* __restrict__ wpart) {
    int bid = blockIdx.x;
    int b   = bid >> 6;
    int rem = bid & 63;
    int nch = rem >> 3;
    int sch = rem & 7;
    int tid = threadIdx.x;
    int c    = tid & 127;
    int half = tid >> 7;
    int n = nch * 128 + c;
    if (n >= NUSE) return;
    int sl = (n < 512) ? 0 : (n < 768) ? 1 : (n < 896) ? 2 : 3;
    int s0 = sch * 256 + half * 128;
    long long rowBase = (long long)b * SEQ + s0;
    const float* Pp = P + rowBase * NUSE + n;
    const float* cp = coef + rowBase * 4 + sl;
    float acc = 0.f;
    #pragma unroll 4
    for (int t = 0; t < 128; t++) {
        acc = fmaf(cp[(long long)t * 4], Pp[(long long)t * NUSE], acc);
    }
    wpart[((long long)(sch * 2 + half) * 8 + b) * NUSE + n] = acc;
}

// ---------------- kernel C: reduce partials, ranks, outputs ----------------
// out layout (floats): idx_qk[8][64] @0, idx_v[8][32] @512, rw_Q[8][128] @768,
// rw_K[8][128] @1792, vw[8][32] @2816, w_qk[8][512] @3072, w_v[8][256] @7168
__global__ __launch_bounds__(512) void k_out(const float* __restrict__ wpart,
                                             float* __restrict__ out) {
    const int b = blockIdx.x;
    const int tid = threadIdx.x;
    __shared__ float w_s[NUSE];
    __shared__ int   rk[NUSE];

    for (int n = tid; n < NUSE; n += 512) {
        float s = 0.f;
        #pragma unroll
        for (int p = 0; p < 16; p++)
            s += wpart[((long long)p * 8 + b) * NUSE + n];
        w_s[n] = s;
        if (n < 512)      out[3072 + (long long)b * 512 + n] = s;
        else if (n < 768) out[7168 + (long long)b * 256 + (n - 512)] = s;
    }
    __syncthreads();

    // stable ranks within each slice (matches lax.top_k tie semantics)
    for (int n = tid; n < NUSE; n += 512) {
        int lo, hi;
        if (n < 512)      { lo = 0;   hi = 512; }
        else if (n < 768) { lo = 512; hi = 768; }
        else if (n < 896) { lo = 768; hi = 896; }
        else              { lo = 896; hi = NUSE; }
        float wn = w_s[n];
        int r = 0;
        for (int m = lo; m < hi; m++) {
            float wm = w_s[m];
            r += (wm > wn) || ((wm == wn) && (m < n));
        }
        rk[n] = r;
    }
    __syncthreads();

    // idx_qk: sorted ascending indices of top-64 of slice0
    if (tid < 512) {
        int n = tid;
        if (rk[n] < 64) {
            int pos = 0;
            for (int m = 0; m < n; m++) pos += (rk[m] < 64) ? 1 : 0;
            out[(long long)b * 64 + pos] = (float)n;
        }
    }
    // idx_v: sorted ascending indices of top-32 of slice1 (local indices)
    if (tid < 256) {
        int n = 512 + tid;
        if (rk[n] < 32) {
            int pos = 0;
            for (int m = 512; m < n; m++) pos += (rk[m] < 32) ? 1 : 0;
            out[512 + (long long)b * 32 + pos] = (float)tid;
        }
    }
    // rw_Q / rw_K: sparsify top-16 of slice2
    if (tid < 128) {
        int n = 768 + tid;
        float v = (rk[n] < 16) ? w_s[n] : 0.f;
        out[768 + (long long)b * 128 + tid] = v;
        out[1792 + (long long)b * 128 + tid] = v;
    }
    // vw: sparsify top-3 of slice3
    if (tid < 32) {
        int n = 896 + tid;
        float v = (rk[n] < 3) ? w_s[n] : 0.f;
        out[2816 + (long long)b * 32 + tid] = v;
    }
}

// ---------------- launch ----------------
extern "C" void kernel_launch(void* const* d_in, const int* in_sizes, int n_in,
                              void* d_out, int out_size, void* d_ws, size_t ws_size,
                              hipStream_t stream) {
    const float* x    = (const float*)d_in[0];
    const float* imp  = (const float*)d_in[1];
    const float* W    = (const float*)d_in[2];
    const float* bias = (const float*)d_in[3];
    const float* emb  = (const float*)d_in[4];

    float* ws    = (float*)d_ws;
    float* EnT   = ws + OFF_ENT;
    float* h     = ws + OFF_H;
    float* P     = ws + OFF_P;
    float* Z     = ws + OFF_Z;
    float* coef  = ws + OFF_CF;
    float* wpart = ws + OFF_WP;
    float* out   = (float*)d_out;

    // Z is accumulated with atomics -> must be zeroed every launch (ws is re-poisoned)
    hipMemsetAsync(Z, 0, (size_t)ROWS * 4 * sizeof(float), stream);

    k_prep<<<4, 256, 0, stream>>>(emb, EnT);
    k_hmm<<<256, 256, 0, stream>>>(x, W, bias, h);
    dim3 gb1(256, 15);
    k_logits<<<gb1, 256, 0, stream>>>(h, EnT, P, Z);
    k_coef<<<64, 256, 0, stream>>>(imp, Z, coef);
    k_wacc<<<512, 256, 0, stream>>>(P, coef, wpart);
    k_out<<<8, 512, 0, stream>>>(wpart, out);
}

// Round 2
// 190.333 us; speedup vs baseline: 1.1985x; 1.1985x over previous
//
#include <hip/hip_runtime.h>
#include <hip/hip_bf16.h>
#include <math.h>

// ---------------- problem constants ----------------
#define ROWS  16384           // B*S
#define DM    1024
#define DS    64
#define NUSE  928             // 512+256+128+32
#define NPAD  960             // padded to 15 tiles of 64
#define NT    15

typedef __attribute__((ext_vector_type(8))) short bf16x8;
typedef __attribute__((ext_vector_type(4))) float f32x4;

static __device__ inline f32x4 mfma16(bf16x8 a, bf16x8 b, f32x4 c) {
    return __builtin_amdgcn_mfma_f32_16x16x32_bf16(a, b, c, 0, 0, 0);
}

// split fp32 -> bf16 hi + bf16 lo (RNE both), v ~= hi + lo to ~2^-18 rel
static __device__ inline void bfsplit(float v, unsigned short& h, unsigned short& l) {
    unsigned u = __float_as_uint(v);
    unsigned hr = u + 0x7FFFu + ((u >> 16) & 1u);
    h = (unsigned short)(hr >> 16);
    float hf = __uint_as_float((unsigned)h << 16);
    float r = v - hf;
    unsigned ur = __float_as_uint(r);
    unsigned lr2 = ur + 0x7FFFu + ((ur >> 16) & 1u);
    l = (unsigned short)(lr2 >> 16);
}

// ---------------- workspace byte offsets ----------------
// EB (emb bf16 frag-linear [kt2][q4][n960][j8]) hi/lo: 122880 B each
// WB (W   bf16 frag-linear [ktg32][q4][n64][j8]) hi/lo: 131072 B each
// HPART fp32 [g8][row 16384][c64]: 32 MB
// HB (h bf16 frag-linear [rc256][kt2][q4][r64][j8]) hi/lo: 2 MB each
// ZPART fp32 [nt15][row 16384]; COEF fp32 [row][4]; WPART fp32 [rc256][960]
#define OFF_EBH  0LL
#define OFF_EBL  122880LL
#define OFF_WBH  245760LL
#define OFF_WBL  376832LL
#define OFF_HP   507904LL
#define OFF_HBH  34062336LL
#define OFF_HBL  36159488LL
#define OFF_ZP   38256640LL
#define OFF_CF   39239680LL
#define OFF_WP   39501824LL
// end 40484864 B (~38.6 MB) < ws_size (>=66 MB per round 0)

// ---------------- k_prep: normalize emb -> Ebf frag-linear ----------------
__global__ __launch_bounds__(256) void k_prep(const float* __restrict__ emb,
                                              unsigned short* __restrict__ ebh,
                                              unsigned short* __restrict__ ebl) {
    int n = blockIdx.x * 256 + threadIdx.x;
    if (n >= NPAD) return;
    if (n >= NUSE) {
        #pragma unroll
        for (int d = 0; d < DS; d++) {
            int kt = d >> 5, q = (d >> 3) & 3, j = d & 7;
            int a = ((kt * 4 + q) * NPAD + n) * 8 + j;
            ebh[a] = 0; ebl[a] = 0;
        }
        return;
    }
    float ss = 0.f;
    #pragma unroll
    for (int d = 0; d < DS; d++) { float v = emb[n * DS + d]; ss = fmaf(v, v, ss); }
    float inv = 1.0f / sqrtf(ss);
    #pragma unroll
    for (int d = 0; d < DS; d++) {
        float v = emb[n * DS + d] * inv;
        unsigned short h, l; bfsplit(v, h, l);
        int kt = d >> 5, q = (d >> 3) & 3, j = d & 7;
        int a = ((kt * 4 + q) * NPAD + n) * 8 + j;
        ebh[a] = h; ebl[a] = l;
    }
}

// ---------------- k_prepw: W -> Wbf frag-linear ----------------
__global__ __launch_bounds__(256) void k_prepw(const float* __restrict__ W,
                                               unsigned short* __restrict__ wbh,
                                               unsigned short* __restrict__ wbl) {
    int idx = blockIdx.x * 256 + threadIdx.x;   // 0..2047
    int ktg = idx >> 6, n = idx & 63;
    #pragma unroll
    for (int q = 0; q < 4; q++) {
        #pragma unroll
        for (int j = 0; j < 8; j++) {
            int k = ktg * 32 + q * 8 + j;
            float v = W[k * DS + n];
            unsigned short h, l; bfsplit(v, h, l);
            int a = ((ktg * 4 + q) * 64 + n) * 8 + j;
            wbh[a] = h; wbl[a] = l;
        }
    }
}

// ---------------- k_hmm: h partials via split-bf16 MFMA ----------------
// grid (256 rowchunks, 8 kchunks of 128). block 256 = 4 waves x (16 rows, 64 cols)
__global__ __launch_bounds__(256) void k_hmm(const float* __restrict__ x,
                                             const unsigned short* __restrict__ wbh,
                                             const unsigned short* __restrict__ wbl,
                                             float* __restrict__ hpart) {
    __shared__ unsigned short Ah[4 * 4 * 64 * 8];   // [kt][q][r][j]
    __shared__ unsigned short Al[4 * 4 * 64 * 8];
    const int tid = threadIdx.x;
    const int rc = blockIdx.x, g = blockIdx.y;
    const long long row0 = (long long)rc * 64;
    const int k0 = g * 128;

    // stage + split x tile [64 rows][128 k]
    {
        int r = tid >> 2, cg = tid & 3;
        const float* xp = &x[(row0 + r) * DM + k0 + cg * 32];
        #pragma unroll
        for (int u = 0; u < 8; u++) {
            float4 v = *(const float4*)&xp[u * 4];
            int q = u >> 1, j0 = (u & 1) * 4;
            int base = ((cg * 4 + q) * 64 + r) * 8 + j0;
            unsigned short h0, l0, h1, l1, h2, l2, h3, l3;
            bfsplit(v.x, h0, l0); bfsplit(v.y, h1, l1);
            bfsplit(v.z, h2, l2); bfsplit(v.w, h3, l3);
            uint2 ph; ph.x = (unsigned)h0 | ((unsigned)h1 << 16); ph.y = (unsigned)h2 | ((unsigned)h3 << 16);
            uint2 pl; pl.x = (unsigned)l0 | ((unsigned)l1 << 16); pl.y = (unsigned)l2 | ((unsigned)l3 << 16);
            *(uint2*)&Ah[base] = ph;
            *(uint2*)&Al[base] = pl;
        }
    }
    __syncthreads();

    const int w = tid >> 6, lane = tid & 63, q = lane >> 4, lm = lane & 15;
    f32x4 acc[4];
    #pragma unroll
    for (int f = 0; f < 4; f++) { acc[f].x = 0.f; acc[f].y = 0.f; acc[f].z = 0.f; acc[f].w = 0.f; }

    #pragma unroll
    for (int kt = 0; kt < 4; kt++) {
        const bf16x8 a_h = *(const bf16x8*)&Ah[((kt * 4 + q) * 64 + w * 16 + lm) * 8];
        const bf16x8 a_l = *(const bf16x8*)&Al[((kt * 4 + q) * 64 + w * 16 + lm) * 8];
        const int ktg = g * 4 + kt;
        #pragma unroll
        for (int f = 0; f < 4; f++) {
            int ba = ((ktg * 4 + q) * 64 + f * 16 + lm) * 8;
            bf16x8 b_h = *(const bf16x8*)&wbh[ba];
            bf16x8 b_l = *(const bf16x8*)&wbl[ba];
            acc[f] = mfma16(a_h, b_h, acc[f]);
            acc[f] = mfma16(a_h, b_l, acc[f]);
            acc[f] = mfma16(a_l, b_h, acc[f]);
        }
    }

    float* hp = &hpart[((long long)g * ROWS + row0) * 64];
    #pragma unroll
    for (int f = 0; f < 4; f++) {
        #pragma unroll
        for (int t = 0; t < 4; t++) {
            hp[(w * 16 + q * 4 + t) * 64 + f * 16 + lm] = acc[f][t];
        }
    }
}

// ---------------- k_hadd: reduce 8 partials + bias -> hbf frag-linear ----------------
__global__ __launch_bounds__(256) void k_hadd(const float* __restrict__ hpart,
                                              const float* __restrict__ bias,
                                              unsigned short* __restrict__ hbh,
                                              unsigned short* __restrict__ hbl) {
    int i = blockIdx.x * 256 + threadIdx.x;   // < 131072
    int gr = i >> 3, qq = i & 7;
    int d0 = qq * 8;
    float4 s0 = *(const float4*)&bias[d0];
    float4 s1 = *(const float4*)&bias[d0 + 4];
    #pragma unroll
    for (int g = 0; g < 8; g++) {
        const float* p = &hpart[((long long)g * ROWS + gr) * 64 + d0];
        float4 a = *(const float4*)&p[0];
        float4 b = *(const float4*)&p[4];
        s0.x += a.x; s0.y += a.y; s0.z += a.z; s0.w += a.w;
        s1.x += b.x; s1.y += b.y; s1.z += b.z; s1.w += b.w;
    }
    unsigned short h[8], l[8];
    bfsplit(s0.x, h[0], l[0]); bfsplit(s0.y, h[1], l[1]);
    bfsplit(s0.z, h[2], l[2]); bfsplit(s0.w, h[3], l[3]);
    bfsplit(s1.x, h[4], l[4]); bfsplit(s1.y, h[5], l[5]);
    bfsplit(s1.z, h[6], l[6]); bfsplit(s1.w, h[7], l[7]);
    int rc = gr >> 6, lr = gr & 63;
    int kt = qq >> 2, q = qq & 3;
    int base = (((rc * 2 + kt) * 4 + q) * 64 + lr) * 8;
    uint4 ph, pl;
    ph.x = (unsigned)h[0] | ((unsigned)h[1] << 16); ph.y = (unsigned)h[2] | ((unsigned)h[3] << 16);
    ph.z = (unsigned)h[4] | ((unsigned)h[5] << 16); ph.w = (unsigned)h[6] | ((unsigned)h[7] << 16);
    pl.x = (unsigned)l[0] | ((unsigned)l[1] << 16); pl.y = (unsigned)l[2] | ((unsigned)l[3] << 16);
    pl.z = (unsigned)l[4] | ((unsigned)l[5] << 16); pl.w = (unsigned)l[6] | ((unsigned)l[7] << 16);
    *(uint4*)&hbh[base] = ph;
    *(uint4*)&hbl[base] = pl;
}

// ---------------- shared logits GEMM core ----------------
static __device__ inline void logits_gemm(const unsigned short* __restrict__ hbh,
                                          const unsigned short* __restrict__ hbl,
                                          const unsigned short* __restrict__ ebh,
                                          const unsigned short* __restrict__ ebl,
                                          int rc, int nt, int w, int q, int lm,
                                          f32x4 acc[4]) {
    #pragma unroll
    for (int f = 0; f < 4; f++) { acc[f].x = 0.f; acc[f].y = 0.f; acc[f].z = 0.f; acc[f].w = 0.f; }
    #pragma unroll
    for (int kt = 0; kt < 2; kt++) {
        int ab = (((rc * 2 + kt) * 4 + q) * 64 + w * 16 + lm) * 8;
        const bf16x8 a_h = *(const bf16x8*)&hbh[ab];
        const bf16x8 a_l = *(const bf16x8*)&hbl[ab];
        #pragma unroll
        for (int f = 0; f < 4; f++) {
            int bb = ((kt * 4 + q) * NPAD + nt * 64 + f * 16 + lm) * 8;
            bf16x8 b_h = *(const bf16x8*)&ebh[bb];
            bf16x8 b_l = *(const bf16x8*)&ebl[bb];
            acc[f] = mfma16(a_h, b_h, acc[f]);
            acc[f] = mfma16(a_h, b_l, acc[f]);
            acc[f] = mfma16(a_l, b_h, acc[f]);
        }
    }
}

// ---------------- k_z: Z partial sums (no P stored) ----------------
// grid (256, 15); zpart[nt][row]
__global__ __launch_bounds__(256) void k_z(const unsigned short* __restrict__ hbh,
                                           const unsigned short* __restrict__ hbl,
                                           const unsigned short* __restrict__ ebh,
                                           const unsigned short* __restrict__ ebl,
                                           float* __restrict__ zpart) {
    const int rc = blockIdx.x, nt = blockIdx.y;
    const int tid = threadIdx.x, w = tid >> 6, lane = tid & 63, q = lane >> 4, lm = lane & 15;
    f32x4 acc[4];
    logits_gemm(hbh, hbl, ebh, ebl, rc, nt, w, q, lm, acc);

    float s0 = 0.f, s1 = 0.f, s2 = 0.f, s3 = 0.f;
    #pragma unroll
    for (int f = 0; f < 4; f++) {
        if (nt * 64 + f * 16 < NUSE) {
            s0 += __expf(acc[f][0]); s1 += __expf(acc[f][1]);
            s2 += __expf(acc[f][2]); s3 += __expf(acc[f][3]);
        }
    }
    #pragma unroll
    for (int off = 1; off < 16; off <<= 1) {
        s0 += __shfl_xor(s0, off); s1 += __shfl_xor(s1, off);
        s2 += __shfl_xor(s2, off); s3 += __shfl_xor(s3, off);
    }
    if (lm < 4) {
        float sv = (lm == 0) ? s0 : (lm == 1) ? s1 : (lm == 2) ? s2 : s3;
        zpart[(long long)nt * ROWS + rc * 64 + w * 16 + q * 4 + lm] = sv;
    }
}

// ---------------- k_coef ----------------
__global__ __launch_bounds__(256) void k_coef(const float* __restrict__ imp,
                                              const float* __restrict__ zpart,
                                              float* __restrict__ coef) {
    int r = blockIdx.x * 256 + threadIdx.x;
    float z0 = 0.f, z1 = 0.f, z2 = 0.f;
    #pragma unroll
    for (int t = 0; t < 8; t++)  z0 += zpart[(long long)t * ROWS + r];
    #pragma unroll
    for (int t = 8; t < 12; t++) z1 += zpart[(long long)t * ROWS + r];
    z2 = zpart[12LL * ROWS + r] + zpart[13LL * ROWS + r];
    float z3 = zpart[14LL * ROWS + r];
    float im = imp[r];
    float4 c; c.x = im / z0; c.y = im / z1; c.z = im / z2; c.w = im / z3;
    *(float4*)&coef[(long long)r * 4] = c;
}

// ---------------- k_pw: recompute logits, weighted accumulate -> wpart ----------------
// grid (256, 15); wpart[rc][960]
__global__ __launch_bounds__(256) void k_pw(const unsigned short* __restrict__ hbh,
                                            const unsigned short* __restrict__ hbl,
                                            const unsigned short* __restrict__ ebh,
                                            const unsigned short* __restrict__ ebl,
                                            const float* __restrict__ coef,
                                            float* __restrict__ wpart) {
    const int rc = blockIdx.x, nt = blockIdx.y;
    const int tid = threadIdx.x, w = tid >> 6, lane = tid & 63, q = lane >> 4, lm = lane & 15;
    f32x4 acc[4];
    logits_gemm(hbh, hbl, ebh, ebl, rc, nt, w, q, lm, acc);

    const int sl = (nt < 8) ? 0 : (nt < 12) ? 1 : (nt < 14) ? 2 : 3;
    const int rbase = rc * 64 + w * 16 + q * 4;
    float c0 = coef[(long long)(rbase + 0) * 4 + sl];
    float c1 = coef[(long long)(rbase + 1) * 4 + sl];
    float c2 = coef[(long long)(rbase + 2) * 4 + sl];
    float c3 = coef[(long long)(rbase + 3) * 4 + sl];

    float wsum[4];
    #pragma unroll
    for (int f = 0; f < 4; f++) {
        wsum[f] = c0 * __expf(acc[f][0]) + c1 * __expf(acc[f][1])
                + c2 * __expf(acc[f][2]) + c3 * __expf(acc[f][3]);
        wsum[f] += __shfl_xor(wsum[f], 16);
        wsum[f] += __shfl_xor(wsum[f], 32);
    }
    __shared__ float wbuf[4][64];
    if (lane < 16) {
        #pragma unroll
        for (int f = 0; f < 4; f++) wbuf[w][f * 16 + lane] = wsum[f];
    }
    __syncthreads();
    if (tid < 64) {
        int n = nt * 64 + tid;
        if (n < NUSE) {
            wpart[(long long)rc * NPAD + n] =
                (wbuf[0][tid] + wbuf[1][tid]) + (wbuf[2][tid] + wbuf[3][tid]);
        }
    }
}

// ---------------- k_out: reduce wpart, ranks, outputs ----------------
__global__ __launch_bounds__(512) void k_out(const float* __restrict__ wpart,
                                             float* __restrict__ out) {
    const int b = blockIdx.x;
    const int tid = threadIdx.x;
    __shared__ float w_s[NUSE];
    __shared__ int   rk[NUSE];

    for (int n = tid; n < NUSE; n += 512) {
        float s = 0.f;
        #pragma unroll 4
        for (int c = 0; c < 32; c++)
            s += wpart[(long long)(b * 32 + c) * NPAD + n];
        w_s[n] = s;
        if (n < 512)      out[3072 + (long long)b * 512 + n] = s;
        else if (n < 768) out[7168 + (long long)b * 256 + (n - 512)] = s;
    }
    __syncthreads();

    for (int n = tid; n < NUSE; n += 512) {
        int lo, hi;
        if (n < 512)      { lo = 0;   hi = 512; }
        else if (n < 768) { lo = 512; hi = 768; }
        else if (n < 896) { lo = 768; hi = 896; }
        else              { lo = 896; hi = NUSE; }
        float wn = w_s[n];
        int r = 0;
        for (int m = lo; m < hi; m++) {
            float wm = w_s[m];
            r += (wm > wn) || ((wm == wn) && (m < n));
        }
        rk[n] = r;
    }
    __syncthreads();

    if (tid < 512) {
        int n = tid;
        if (rk[n] < 64) {
            int pos = 0;
            for (int m = 0; m < n; m++) pos += (rk[m] < 64) ? 1 : 0;
            out[(long long)b * 64 + pos] = (float)n;
        }
    }
    if (tid < 256) {
        int n = 512 + tid;
        if (rk[n] < 32) {
            int pos = 0;
            for (int m = 512; m < n; m++) pos += (rk[m] < 32) ? 1 : 0;
            out[512 + (long long)b * 32 + pos] = (float)tid;
        }
    }
    if (tid < 128) {
        int n = 768 + tid;
        float v = (rk[n] < 16) ? w_s[n] : 0.f;
        out[768 + (long long)b * 128 + tid] = v;
        out[1792 + (long long)b * 128 + tid] = v;
    }
    if (tid < 32) {
        int n = 896 + tid;
        float v = (rk[n] < 3) ? w_s[n] : 0.f;
        out[2816 + (long long)b * 32 + tid] = v;
    }
}

// ---------------- launch ----------------
extern "C" void kernel_launch(void* const* d_in, const int* in_sizes, int n_in,
                              void* d_out, int out_size, void* d_ws, size_t ws_size,
                              hipStream_t stream) {
    const float* x    = (const float*)d_in[0];
    const float* imp  = (const float*)d_in[1];
    const float* W    = (const float*)d_in[2];
    const float* bias = (const float*)d_in[3];
    const float* emb  = (const float*)d_in[4];

    char* ws = (char*)d_ws;
    unsigned short* ebh = (unsigned short*)(ws + OFF_EBH);
    unsigned short* ebl = (unsigned short*)(ws + OFF_EBL);
    unsigned short* wbh = (unsigned short*)(ws + OFF_WBH);
    unsigned short* wbl = (unsigned short*)(ws + OFF_WBL);
    float* hpart        = (float*)(ws + OFF_HP);
    unsigned short* hbh = (unsigned short*)(ws + OFF_HBH);
    unsigned short* hbl = (unsigned short*)(ws + OFF_HBL);
    float* zpart        = (float*)(ws + OFF_ZP);
    float* coef         = (float*)(ws + OFF_CF);
    float* wpart        = (float*)(ws + OFF_WP);
    float* out          = (float*)d_out;

    k_prep<<<4, 256, 0, stream>>>(emb, ebh, ebl);
    k_prepw<<<8, 256, 0, stream>>>(W, wbh, wbl);
    k_hmm<<<dim3(256, 8), 256, 0, stream>>>(x, wbh, wbl, hpart);
    k_hadd<<<512, 256, 0, stream>>>(hpart, bias, hbh, hbl);
    k_z<<<dim3(256, NT), 256, 0, stream>>>(hbh, hbl, ebh, ebl, zpart);
    k_coef<<<64, 256, 0, stream>>>(imp, zpart, coef);
    k_pw<<<dim3(256, NT), 256, 0, stream>>>(hbh, hbl, ebh, ebl, coef, wpart);
    k_out<<<8, 512, 0, stream>>>(wpart, out);
}

// Round 3
// 167.008 us; speedup vs baseline: 1.3659x; 1.1397x over previous
//
#include <hip/hip_runtime.h>
#include <hip/hip_bf16.h>
#include <hip/hip_fp16.h>
#include <math.h>

// ---------------- problem constants ----------------
#define ROWS  16384           // B*S
#define DM    1024
#define DS    64
#define NUSE  928             // 512+256+128+32
#define NPAD  960             // padded to 15 tiles of 64
#define NT    15

typedef __attribute__((ext_vector_type(8))) short bf16x8;
typedef __attribute__((ext_vector_type(4))) float f32x4;

static __device__ inline f32x4 mfma16(bf16x8 a, bf16x8 b, f32x4 c) {
    return __builtin_amdgcn_mfma_f32_16x16x32_bf16(a, b, c, 0, 0, 0);
}

// split fp32 -> bf16 hi + bf16 lo (RNE both), v ~= hi + lo to ~2^-18 rel
static __device__ inline void bfsplit(float v, unsigned short& h, unsigned short& l) {
    unsigned u = __float_as_uint(v);
    unsigned hr = u + 0x7FFFu + ((u >> 16) & 1u);
    h = (unsigned short)(hr >> 16);
    float hf = __uint_as_float((unsigned)h << 16);
    float r = v - hf;
    unsigned ur = __float_as_uint(r);
    unsigned lr2 = ur + 0x7FFFu + ((ur >> 16) & 1u);
    l = (unsigned short)(lr2 >> 16);
}

// ---------------- workspace byte offsets ----------------
// eb frag-linear [kt2][q4][n960][j8] hi/lo: 122880 B each
// wb frag-linear [ktg32][q4][n64][j8] hi/lo: 131072 B each
// hpart fp32 [g4][row 16384][64]: 16 MB
// wpart fp32 [rc256][960]
#define OFF_EBH  0LL
#define OFF_EBL  122880LL
#define OFF_WBH  245760LL
#define OFF_WBL  376832LL
#define OFF_HP   507904LL
#define OFF_WP   17285120LL
// end 18268160 B (~17.4 MB)

// ---------------- k_prep: emb normalize+split AND W split (merged) ----------------
__global__ __launch_bounds__(256) void k_prep(const float* __restrict__ emb,
                                              const float* __restrict__ W,
                                              unsigned short* __restrict__ ebh,
                                              unsigned short* __restrict__ ebl,
                                              unsigned short* __restrict__ wbh,
                                              unsigned short* __restrict__ wbl) {
    if (blockIdx.x < 4) {
        int n = blockIdx.x * 256 + threadIdx.x;
        if (n >= NPAD) return;
        if (n >= NUSE) {
            #pragma unroll
            for (int d = 0; d < DS; d++) {
                int kt = d >> 5, q = (d >> 3) & 3, j = d & 7;
                int a = ((kt * 4 + q) * NPAD + n) * 8 + j;
                ebh[a] = 0; ebl[a] = 0;
            }
            return;
        }
        float ss = 0.f;
        #pragma unroll
        for (int d = 0; d < DS; d++) { float v = emb[n * DS + d]; ss = fmaf(v, v, ss); }
        float inv = 1.0f / sqrtf(ss);
        #pragma unroll
        for (int d = 0; d < DS; d++) {
            float v = emb[n * DS + d] * inv;
            unsigned short h, l; bfsplit(v, h, l);
            int kt = d >> 5, q = (d >> 3) & 3, j = d & 7;
            int a = ((kt * 4 + q) * NPAD + n) * 8 + j;
            ebh[a] = h; ebl[a] = l;
        }
    } else {
        int idx = (blockIdx.x - 4) * 256 + threadIdx.x;   // 0..2047
        int ktg = idx >> 6, n = idx & 63;
        #pragma unroll
        for (int q = 0; q < 4; q++) {
            #pragma unroll
            for (int j = 0; j < 8; j++) {
                int k = ktg * 32 + q * 8 + j;
                float v = W[k * DS + n];
                unsigned short h, l; bfsplit(v, h, l);
                int a = ((ktg * 4 + q) * 64 + n) * 8 + j;
                wbh[a] = h; wbl[a] = l;
            }
        }
    }
}

// ---------------- k_hmm: h partials via split-bf16 MFMA ----------------
// grid (256 rowchunks, 4 kchunks of 256). block 256 = 4 waves x (16 rows, 64 cols)
__global__ __launch_bounds__(256, 4) void k_hmm(const float* __restrict__ x,
                                                const unsigned short* __restrict__ wbh,
                                                const unsigned short* __restrict__ wbl,
                                                float* __restrict__ hpart) {
    __shared__ unsigned short Ah[4 * 4 * 64 * 8];   // [ktL][q][r][j] for a 128-k chunk
    __shared__ unsigned short Al[4 * 4 * 64 * 8];
    const int tid = threadIdx.x;
    const int rc = blockIdx.x, g = blockIdx.y;
    const long long row0 = (long long)rc * 64;

    const int sr = tid >> 2, scg = tid & 3;
    const float* xrow = &x[(row0 + sr) * DM + g * 256 + scg * 32];

    const int w = tid >> 6, lane = tid & 63, q = lane >> 4, lm = lane & 15;
    f32x4 acc[4];
    #pragma unroll
    for (int f = 0; f < 4; f++) { acc[f].x = 0.f; acc[f].y = 0.f; acc[f].z = 0.f; acc[f].w = 0.f; }

    // ---- stage chunk 0 ----
    float4 pf[8];
    #pragma unroll
    for (int u = 0; u < 8; u++) pf[u] = *(const float4*)&xrow[u * 4];
    #pragma unroll
    for (int u = 0; u < 8; u++) {
        int qq = u >> 1, j0 = (u & 1) * 4;
        int base = ((scg * 4 + qq) * 64 + sr) * 8 + j0;
        unsigned short h0, l0, h1, l1, h2, l2, h3, l3;
        bfsplit(pf[u].x, h0, l0); bfsplit(pf[u].y, h1, l1);
        bfsplit(pf[u].z, h2, l2); bfsplit(pf[u].w, h3, l3);
        uint2 ph; ph.x = (unsigned)h0 | ((unsigned)h1 << 16); ph.y = (unsigned)h2 | ((unsigned)h3 << 16);
        uint2 pl; pl.x = (unsigned)l0 | ((unsigned)l1 << 16); pl.y = (unsigned)l2 | ((unsigned)l3 << 16);
        *(uint2*)&Ah[base] = ph;
        *(uint2*)&Al[base] = pl;
    }
    __syncthreads();

    // ---- prefetch chunk 1 while computing chunk 0 ----
    #pragma unroll
    for (int u = 0; u < 8; u++) pf[u] = *(const float4*)&xrow[128 + u * 4];

    #pragma unroll
    for (int kt = 0; kt < 4; kt++) {
        const bf16x8 a_h = *(const bf16x8*)&Ah[((kt * 4 + q) * 64 + w * 16 + lm) * 8];
        const bf16x8 a_l = *(const bf16x8*)&Al[((kt * 4 + q) * 64 + w * 16 + lm) * 8];
        const int ktg = g * 8 + kt;
        #pragma unroll
        for (int f = 0; f < 4; f++) {
            int ba = ((ktg * 4 + q) * 64 + f * 16 + lm) * 8;
            bf16x8 b_h = *(const bf16x8*)&wbh[ba];
            bf16x8 b_l = *(const bf16x8*)&wbl[ba];
            acc[f] = mfma16(a_h, b_h, acc[f]);
            acc[f] = mfma16(a_h, b_l, acc[f]);
            acc[f] = mfma16(a_l, b_h, acc[f]);
        }
    }
    __syncthreads();

    // ---- stage chunk 1 ----
    #pragma unroll
    for (int u = 0; u < 8; u++) {
        int qq = u >> 1, j0 = (u & 1) * 4;
        int base = ((scg * 4 + qq) * 64 + sr) * 8 + j0;
        unsigned short h0, l0, h1, l1, h2, l2, h3, l3;
        bfsplit(pf[u].x, h0, l0); bfsplit(pf[u].y, h1, l1);
        bfsplit(pf[u].z, h2, l2); bfsplit(pf[u].w, h3, l3);
        uint2 ph; ph.x = (unsigned)h0 | ((unsigned)h1 << 16); ph.y = (unsigned)h2 | ((unsigned)h3 << 16);
        uint2 pl; pl.x = (unsigned)l0 | ((unsigned)l1 << 16); pl.y = (unsigned)l2 | ((unsigned)l3 << 16);
        *(uint2*)&Ah[base] = ph;
        *(uint2*)&Al[base] = pl;
    }
    __syncthreads();

    #pragma unroll
    for (int kt = 0; kt < 4; kt++) {
        const bf16x8 a_h = *(const bf16x8*)&Ah[((kt * 4 + q) * 64 + w * 16 + lm) * 8];
        const bf16x8 a_l = *(const bf16x8*)&Al[((kt * 4 + q) * 64 + w * 16 + lm) * 8];
        const int ktg = g * 8 + 4 + kt;
        #pragma unroll
        for (int f = 0; f < 4; f++) {
            int ba = ((ktg * 4 + q) * 64 + f * 16 + lm) * 8;
            bf16x8 b_h = *(const bf16x8*)&wbh[ba];
            bf16x8 b_l = *(const bf16x8*)&wbl[ba];
            acc[f] = mfma16(a_h, b_h, acc[f]);
            acc[f] = mfma16(a_h, b_l, acc[f]);
            acc[f] = mfma16(a_l, b_h, acc[f]);
        }
    }

    float* hp = &hpart[((long long)g * ROWS + row0) * 64];
    #pragma unroll
    for (int f = 0; f < 4; f++) {
        #pragma unroll
        for (int t = 0; t < 4; t++) {
            hp[(w * 16 + q * 4 + t) * 64 + f * 16 + lm] = acc[f][t];
        }
    }
}

// ---------------- k_zpw: fused h-reduce + logits + softmax-Z + weighted col-reduce ----------------
// grid 256 (one per 64-row chunk), 1024 threads = 16 waves = 4 rw-groups x 4 wave-groups
__global__ __launch_bounds__(1024, 4) void k_zpw(const float* __restrict__ hpart,
                                                 const float* __restrict__ bias,
                                                 const unsigned short* __restrict__ ebh,
                                                 const unsigned short* __restrict__ ebl,
                                                 const float* __restrict__ imp,
                                                 float* __restrict__ wpart) {
    __shared__ __align__(16) unsigned short Ph[NPAD * 72];   // P fp16, [n][row], row-stride 72
    __shared__ __align__(16) unsigned short Ah[2 * 4 * 64 * 8];  // h split, [kt][q][r][j]
    __shared__ __align__(16) unsigned short Al[2 * 4 * 64 * 8];
    __shared__ float zslot[4][4][64];    // [wavegroup][slice][row]
    __shared__ float coefL[64 * 4];

    const int tid = threadIdx.x;
    const int rc = blockIdx.x;

    // ---- zero zslot ----
    if (tid < 1024) ((float*)zslot)[tid] = 0.f;

    // ---- A-prep: reduce hpart + bias, split to LDS ----
    {
        int r = tid >> 4, seg = tid & 15;
        int col = seg * 4;
        float4 s = *(const float4*)&bias[col];
        #pragma unroll
        for (int g = 0; g < 4; g++) {
            float4 a = *(const float4*)&hpart[((long long)g * ROWS + rc * 64 + r) * 64 + col];
            s.x += a.x; s.y += a.y; s.z += a.z; s.w += a.w;
        }
        unsigned short h0, l0, h1, l1, h2, l2, h3, l3;
        bfsplit(s.x, h0, l0); bfsplit(s.y, h1, l1);
        bfsplit(s.z, h2, l2); bfsplit(s.w, h3, l3);
        int kt = seg >> 3, q = (seg >> 1) & 3, j0 = (seg & 1) * 4;
        int base = ((kt * 4 + q) * 64 + r) * 8 + j0;
        uint2 ph; ph.x = (unsigned)h0 | ((unsigned)h1 << 16); ph.y = (unsigned)h2 | ((unsigned)h3 << 16);
        uint2 pl; pl.x = (unsigned)l0 | ((unsigned)l1 << 16); pl.y = (unsigned)l2 | ((unsigned)l3 << 16);
        *(uint2*)&Ah[base] = ph;
        *(uint2*)&Al[base] = pl;
    }
    __syncthreads();

    // ---- phase 1: logits GEMM, exp, P->LDS, z partial sums ----
    const int w = tid >> 6, lane = tid & 63, q = lane >> 4, lm = lane & 15;
    const int rw = w & 3, wg = w >> 2;

    bf16x8 a_h[2], a_l[2];
    #pragma unroll
    for (int kt = 0; kt < 2; kt++) {
        int ab = ((kt * 4 + q) * 64 + rw * 16 + lm) * 8;
        a_h[kt] = *(const bf16x8*)&Ah[ab];
        a_l[kt] = *(const bf16x8*)&Al[ab];
    }

    #pragma unroll
    for (int v = 0; v < 4; v++) {
        int nt = wg + v * 4;
        if (nt > 14) continue;
        f32x4 acc[4];
        #pragma unroll
        for (int f = 0; f < 4; f++) { acc[f].x = 0.f; acc[f].y = 0.f; acc[f].z = 0.f; acc[f].w = 0.f; }
        #pragma unroll
        for (int kt = 0; kt < 2; kt++) {
            #pragma unroll
            for (int f = 0; f < 4; f++) {
                int bb = ((kt * 4 + q) * NPAD + nt * 64 + f * 16 + lm) * 8;
                bf16x8 b_h = *(const bf16x8*)&ebh[bb];
                bf16x8 b_l = *(const bf16x8*)&ebl[bb];
                acc[f] = mfma16(a_h[kt], b_h, acc[f]);
                acc[f] = mfma16(a_h[kt], b_l, acc[f]);
                acc[f] = mfma16(a_l[kt], b_h, acc[f]);
            }
        }
        const int sl = (nt < 8) ? 0 : (nt < 12) ? 1 : (nt < 14) ? 2 : 3;
        float s0 = 0.f, s1 = 0.f, s2 = 0.f, s3 = 0.f;
        #pragma unroll
        for (int f = 0; f < 4; f++) {
            float e0 = __expf(acc[f][0]);
            float e1 = __expf(acc[f][1]);
            float e2 = __expf(acc[f][2]);
            float e3 = __expf(acc[f][3]);
            // store P (fp16) at [n][row]
            int n = nt * 64 + f * 16 + lm;
            unsigned short p0 = __half_as_ushort(__float2half(e0));
            unsigned short p1 = __half_as_ushort(__float2half(e1));
            unsigned short p2 = __half_as_ushort(__float2half(e2));
            unsigned short p3 = __half_as_ushort(__float2half(e3));
            uint2 pk; pk.x = (unsigned)p0 | ((unsigned)p1 << 16); pk.y = (unsigned)p2 | ((unsigned)p3 << 16);
            *(uint2*)&Ph[n * 72 + rw * 16 + q * 4] = pk;
            if (nt * 64 + f * 16 < NUSE) {   // exclude pad cols (nt14 f2,f3) from Z
                s0 += e0; s1 += e1; s2 += e2; s3 += e3;
            }
        }
        #pragma unroll
        for (int off = 1; off < 16; off <<= 1) {
            s0 += __shfl_xor(s0, off); s1 += __shfl_xor(s1, off);
            s2 += __shfl_xor(s2, off); s3 += __shfl_xor(s3, off);
        }
        if (lm < 4) {
            float sv = (lm == 0) ? s0 : (lm == 1) ? s1 : (lm == 2) ? s2 : s3;
            zslot[wg][sl][rw * 16 + q * 4 + lm] += sv;   // same lane across v-iters: no race
        }
    }
    __syncthreads();

    // ---- Z + coef ----
    if (tid < 64) {
        int r = tid;
        float im = imp[rc * 64 + r];
        #pragma unroll
        for (int sl = 0; sl < 4; sl++) {
            float Z = zslot[0][sl][r] + zslot[1][sl][r] + zslot[2][sl][r] + zslot[3][sl][r];
            coefL[r * 4 + sl] = im / Z;
        }
    }
    __syncthreads();

    // ---- phase 2: weighted column reduce ----
    if (tid < NUSE) {
        int n = tid;
        int sl = (n < 512) ? 0 : (n < 768) ? 1 : (n < 896) ? 2 : 3;
        float acc = 0.f;
        #pragma unroll
        for (int rb = 0; rb < 8; rb++) {
            uint4 pk = *(const uint4*)&Ph[n * 72 + rb * 8];
            const unsigned pv[4] = {pk.x, pk.y, pk.z, pk.w};
            #pragma unroll
            for (int u = 0; u < 4; u++) {
                float v0 = __half2float(__ushort_as_half((unsigned short)(pv[u] & 0xFFFF)));
                float v1 = __half2float(__ushort_as_half((unsigned short)(pv[u] >> 16)));
                int row = rb * 8 + u * 2;
                acc = fmaf(coefL[(row + 0) * 4 + sl], v0, acc);
                acc = fmaf(coefL[(row + 1) * 4 + sl], v1, acc);
            }
        }
        wpart[(long long)rc * NPAD + n] = acc;
    }
}

// ---------------- k_out: reduce wpart, ranks, outputs ----------------
__global__ __launch_bounds__(512) void k_out(const float* __restrict__ wpart,
                                             float* __restrict__ out) {
    const int b = blockIdx.x;
    const int tid = threadIdx.x;
    __shared__ float w_s[NUSE];
    __shared__ int   rk[NUSE];

    for (int n = tid; n < NUSE; n += 512) {
        float s = 0.f;
        #pragma unroll 4
        for (int c = 0; c < 32; c++)
            s += wpart[(long long)(b * 32 + c) * NPAD + n];
        w_s[n] = s;
        if (n < 512)      out[3072 + (long long)b * 512 + n] = s;
        else if (n < 768) out[7168 + (long long)b * 256 + (n - 512)] = s;
    }
    __syncthreads();

    for (int n = tid; n < NUSE; n += 512) {
        int lo, hi;
        if (n < 512)      { lo = 0;   hi = 512; }
        else if (n < 768) { lo = 512; hi = 768; }
        else if (n < 896) { lo = 768; hi = 896; }
        else              { lo = 896; hi = NUSE; }
        float wn = w_s[n];
        int r = 0;
        for (int m = lo; m < hi; m++) {
            float wm = w_s[m];
            r += (wm > wn) || ((wm == wn) && (m < n));
        }
        rk[n] = r;
    }
    __syncthreads();

    if (tid < 512) {
        int n = tid;
        if (rk[n] < 64) {
            int pos = 0;
            for (int m = 0; m < n; m++) pos += (rk[m] < 64) ? 1 : 0;
            out[(long long)b * 64 + pos] = (float)n;
        }
    }
    if (tid < 256) {
        int n = 512 + tid;
        if (rk[n] < 32) {
            int pos = 0;
            for (int m = 512; m < n; m++) pos += (rk[m] < 32) ? 1 : 0;
            out[512 + (long long)b * 32 + pos] = (float)tid;
        }
    }
    if (tid < 128) {
        int n = 768 + tid;
        float v = (rk[n] < 16) ? w_s[n] : 0.f;
        out[768 + (long long)b * 128 + tid] = v;
        out[1792 + (long long)b * 128 + tid] = v;
    }
    if (tid < 32) {
        int n = 896 + tid;
        float v = (rk[n] < 3) ? w_s[n] : 0.f;
        out[2816 + (long long)b * 32 + tid] = v;
    }
}

// ---------------- launch ----------------
extern "C" void kernel_launch(void* const* d_in, const int* in_sizes, int n_in,
                              void* d_out, int out_size, void* d_ws, size_t ws_size,
                              hipStream_t stream) {
    const float* x    = (const float*)d_in[0];
    const float* imp  = (const float*)d_in[1];
    const float* W    = (const float*)d_in[2];
    const float* bias = (const float*)d_in[3];
    const float* emb  = (const float*)d_in[4];

    char* ws = (char*)d_ws;
    unsigned short* ebh = (unsigned short*)(ws + OFF_EBH);
    unsigned short* ebl = (unsigned short*)(ws + OFF_EBL);
    unsigned short* wbh = (unsigned short*)(ws + OFF_WBH);
    unsigned short* wbl = (unsigned short*)(ws + OFF_WBL);
    float* hpart        = (float*)(ws + OFF_HP);
    float* wpart        = (float*)(ws + OFF_WP);
    float* out          = (float*)d_out;

    k_prep<<<12, 256, 0, stream>>>(emb, W, ebh, ebl, wbh, wbl);
    k_hmm<<<dim3(256, 4), 256, 0, stream>>>(x, wbh, wbl, hpart);
    k_zpw<<<256, 1024, 0, stream>>>(hpart, bias, ebh, ebl, imp, wpart);
    k_out<<<8, 512, 0, stream>>>(wpart, out);
}

// Round 4
// 158.621 us; speedup vs baseline: 1.4382x; 1.0529x over previous
//
#include <hip/hip_runtime.h>
#include <hip/hip_bf16.h>
#include <hip/hip_fp16.h>
#include <math.h>

// ---------------- problem constants ----------------
#define ROWS  16384           // B*S
#define DM    1024
#define DS    64
#define NUSE  928             // 512+256+128+32
#define NPAD  960             // padded to 15 tiles of 64
#define NT    15

typedef __attribute__((ext_vector_type(8))) short bf16x8;
typedef __attribute__((ext_vector_type(4))) float f32x4;

static __device__ inline f32x4 mfma16(bf16x8 a, bf16x8 b, f32x4 c) {
    return __builtin_amdgcn_mfma_f32_16x16x32_bf16(a, b, c, 0, 0, 0);
}

// split fp32 -> bf16 hi + bf16 lo (RNE both), v ~= hi + lo to ~2^-18 rel
static __device__ inline void bfsplit(float v, unsigned short& h, unsigned short& l) {
    unsigned u = __float_as_uint(v);
    unsigned hr = u + 0x7FFFu + ((u >> 16) & 1u);
    h = (unsigned short)(hr >> 16);
    float hf = __uint_as_float((unsigned)h << 16);
    float r = v - hf;
    unsigned ur = __float_as_uint(r);
    unsigned lr2 = ur + 0x7FFFu + ((ur >> 16) & 1u);
    l = (unsigned short)(lr2 >> 16);
}

// ---------------- workspace byte offsets ----------------
// eb frag-linear [kt2][q4][n960][j8] hi/lo: 122880 B each
// wb frag-linear [ktg32][q4][n64][j8] hi/lo: 131072 B each
// wpart fp32 [rc256][960]
#define OFF_EBH  0LL
#define OFF_EBL  122880LL
#define OFF_WBH  245760LL
#define OFF_WBL  376832LL
#define OFF_WP   507904LL
// end 1490944 B (~1.4 MB)

// ---------------- k_prep: emb normalize+split AND W split (merged) ----------------
__global__ __launch_bounds__(256) void k_prep(const float* __restrict__ emb,
                                              const float* __restrict__ W,
                                              unsigned short* __restrict__ ebh,
                                              unsigned short* __restrict__ ebl,
                                              unsigned short* __restrict__ wbh,
                                              unsigned short* __restrict__ wbl) {
    if (blockIdx.x < 4) {
        int n = blockIdx.x * 256 + threadIdx.x;
        if (n >= NPAD) return;
        if (n >= NUSE) {
            #pragma unroll
            for (int d = 0; d < DS; d++) {
                int kt = d >> 5, q = (d >> 3) & 3, j = d & 7;
                int a = ((kt * 4 + q) * NPAD + n) * 8 + j;
                ebh[a] = 0; ebl[a] = 0;
            }
            return;
        }
        float ss = 0.f;
        #pragma unroll
        for (int d = 0; d < DS; d++) { float v = emb[n * DS + d]; ss = fmaf(v, v, ss); }
        float inv = 1.0f / sqrtf(ss);
        #pragma unroll
        for (int d = 0; d < DS; d++) {
            float v = emb[n * DS + d] * inv;
            unsigned short h, l; bfsplit(v, h, l);
            int kt = d >> 5, q = (d >> 3) & 3, j = d & 7;
            int a = ((kt * 4 + q) * NPAD + n) * 8 + j;
            ebh[a] = h; ebl[a] = l;
        }
    } else {
        int idx = (blockIdx.x - 4) * 256 + threadIdx.x;   // 0..2047
        int ktg = idx >> 6, n = idx & 63;
        #pragma unroll
        for (int q = 0; q < 4; q++) {
            #pragma unroll
            for (int j = 0; j < 8; j++) {
                int k = ktg * 32 + q * 8 + j;
                float v = W[k * DS + n];
                unsigned short h, l; bfsplit(v, h, l);
                int a = ((ktg * 4 + q) * 64 + n) * 8 + j;
                wbh[a] = h; wbl[a] = l;
            }
        }
    }
}

// ---------------- k_mega: x@W+b -> logits -> softmax-Z -> weighted col-reduce ----------------
// grid 256 (one per 64-row chunk), 1024 threads = 16 waves.
// Phase A: 16 waves = 4 rowgroups x 4 colgroups, each owns a 16x16 h-tile, K=1024
//          streamed through LDS in 8 chunks of 128 (x-stage aliases Ph region).
// Phase 1: 16 waves = 4 rowgroups x 4 ntile-groups, logits MFMA + exp -> Ph(fp16) + Z.
// Phase 2: 928 threads weighted column reduce -> wpart.
__global__ __launch_bounds__(1024, 4) void k_mega(const float* __restrict__ x,
                                                  const float* __restrict__ bias,
                                                  const unsigned short* __restrict__ wbh,
                                                  const unsigned short* __restrict__ wbl,
                                                  const unsigned short* __restrict__ ebh,
                                                  const unsigned short* __restrict__ ebl,
                                                  const float* __restrict__ imp,
                                                  float* __restrict__ wpart) {
    __shared__ __align__(16) unsigned char smem[159744];
    unsigned short* Ph = (unsigned short*)smem;                 // [n960][72] fp16 (phase 1/2)
    unsigned short* Xh = (unsigned short*)smem;                 // [kt4][q4][r64][j8] (phase A)
    unsigned short* Xl = (unsigned short*)(smem + 16384);
    unsigned short* Hh = (unsigned short*)(smem + 138240);      // [kt2][q4][r64][j8]
    unsigned short* Hl = (unsigned short*)(smem + 146432);
    float* zslot = (float*)(smem + 154624);                     // [wg4][sl4][r64]
    float* coefL = (float*)(smem + 158720);                     // [r64][sl4]

    const int tid = threadIdx.x;
    const int rc = blockIdx.x;
    const long long row0 = (long long)rc * 64;

    zslot[tid & 1023] = 0.f;   // 1024 floats exactly

    const int w = tid >> 6, lane = tid & 63, q = lane >> 4, lm = lane & 15;

    // ======== phase A: h = x@W + b ========
    const int rg = w >> 2, cg = w & 3;
    const int sr = tid >> 4, ss = tid & 15;
    const float* xrow = &x[(row0 + sr) * DM + ss * 8];
    const int skt = ss >> 2, sq = ss & 3;
    const int sbase = ((skt * 4 + sq) * 64 + sr) * 8;

    f32x4 hacc;
    hacc.x = 0.f; hacc.y = 0.f; hacc.z = 0.f; hacc.w = 0.f;

    float4 pf0 = *(const float4*)&xrow[0];
    float4 pf1 = *(const float4*)&xrow[4];

    for (int ch = 0; ch < 8; ch++) {
        if (ch) __syncthreads();          // previous chunk's readers done
        // stage current chunk (split to bf16 hi/lo)
        {
            unsigned short h0, l0, h1, l1, h2, l2, h3, l3;
            bfsplit(pf0.x, h0, l0); bfsplit(pf0.y, h1, l1);
            bfsplit(pf0.z, h2, l2); bfsplit(pf0.w, h3, l3);
            uint2 ph; ph.x = (unsigned)h0 | ((unsigned)h1 << 16); ph.y = (unsigned)h2 | ((unsigned)h3 << 16);
            uint2 pl; pl.x = (unsigned)l0 | ((unsigned)l1 << 16); pl.y = (unsigned)l2 | ((unsigned)l3 << 16);
            *(uint2*)&Xh[sbase] = ph;
            *(uint2*)&Xl[sbase] = pl;
            bfsplit(pf1.x, h0, l0); bfsplit(pf1.y, h1, l1);
            bfsplit(pf1.z, h2, l2); bfsplit(pf1.w, h3, l3);
            ph.x = (unsigned)h0 | ((unsigned)h1 << 16); ph.y = (unsigned)h2 | ((unsigned)h3 << 16);
            pl.x = (unsigned)l0 | ((unsigned)l1 << 16); pl.y = (unsigned)l2 | ((unsigned)l3 << 16);
            *(uint2*)&Xh[sbase + 4] = ph;
            *(uint2*)&Xl[sbase + 4] = pl;
        }
        // prefetch next chunk
        if (ch < 7) {
            pf0 = *(const float4*)&xrow[(ch + 1) * 128];
            pf1 = *(const float4*)&xrow[(ch + 1) * 128 + 4];
        }
        __syncthreads();
        #pragma unroll
        for (int kt = 0; kt < 4; kt++) {
            const bf16x8 a_h = *(const bf16x8*)&Xh[((kt * 4 + q) * 64 + rg * 16 + lm) * 8];
            const bf16x8 a_l = *(const bf16x8*)&Xl[((kt * 4 + q) * 64 + rg * 16 + lm) * 8];
            const int ktg = ch * 4 + kt;
            const int ba = ((ktg * 4 + q) * 64 + cg * 16 + lm) * 8;
            const bf16x8 b_h = *(const bf16x8*)&wbh[ba];
            const bf16x8 b_l = *(const bf16x8*)&wbl[ba];
            hacc = mfma16(a_h, b_h, hacc);
            hacc = mfma16(a_h, b_l, hacc);
            hacc = mfma16(a_l, b_h, hacc);
        }
    }
    __syncthreads();   // phase A fully done; X region becomes Ph

    // write h fragments (bias + split) into dedicated H region
    {
        const int D = cg * 16 + lm;
        const float bv = bias[D];
        const int ktD = D >> 5, qD = (D >> 3) & 3, jD = D & 7;
        #pragma unroll
        for (int t = 0; t < 4; t++) {
            const int R = rg * 16 + q * 4 + t;
            float v = hacc[t] + bv;
            unsigned short hh, ll; bfsplit(v, hh, ll);
            Hh[((ktD * 4 + qD) * 64 + R) * 8 + jD] = hh;
            Hl[((ktD * 4 + qD) * 64 + R) * 8 + jD] = ll;
        }
    }
    __syncthreads();

    // ======== phase 1: logits + exp -> Ph, Z partials ========
    const int rw = w & 3, wg = w >> 2;

    bf16x8 a_h[2], a_l[2];
    #pragma unroll
    for (int kt = 0; kt < 2; kt++) {
        int ab = ((kt * 4 + q) * 64 + rw * 16 + lm) * 8;
        a_h[kt] = *(const bf16x8*)&Hh[ab];
        a_l[kt] = *(const bf16x8*)&Hl[ab];
    }

    #pragma unroll
    for (int v = 0; v < 4; v++) {
        int nt = wg + v * 4;
        if (nt > 14) continue;
        f32x4 acc[4];
        #pragma unroll
        for (int f = 0; f < 4; f++) { acc[f].x = 0.f; acc[f].y = 0.f; acc[f].z = 0.f; acc[f].w = 0.f; }
        #pragma unroll
        for (int kt = 0; kt < 2; kt++) {
            #pragma unroll
            for (int f = 0; f < 4; f++) {
                int bb = ((kt * 4 + q) * NPAD + nt * 64 + f * 16 + lm) * 8;
                bf16x8 b_h = *(const bf16x8*)&ebh[bb];
                bf16x8 b_l = *(const bf16x8*)&ebl[bb];
                acc[f] = mfma16(a_h[kt], b_h, acc[f]);
                acc[f] = mfma16(a_h[kt], b_l, acc[f]);
                acc[f] = mfma16(a_l[kt], b_h, acc[f]);
            }
        }
        const int sl = (nt < 8) ? 0 : (nt < 12) ? 1 : (nt < 14) ? 2 : 3;
        float s0 = 0.f, s1 = 0.f, s2 = 0.f, s3 = 0.f;
        #pragma unroll
        for (int f = 0; f < 4; f++) {
            float e0 = __expf(acc[f][0]);
            float e1 = __expf(acc[f][1]);
            float e2 = __expf(acc[f][2]);
            float e3 = __expf(acc[f][3]);
            int n = nt * 64 + f * 16 + lm;
            unsigned short p0 = __half_as_ushort(__float2half(e0));
            unsigned short p1 = __half_as_ushort(__float2half(e1));
            unsigned short p2 = __half_as_ushort(__float2half(e2));
            unsigned short p3 = __half_as_ushort(__float2half(e3));
            uint2 pk; pk.x = (unsigned)p0 | ((unsigned)p1 << 16); pk.y = (unsigned)p2 | ((unsigned)p3 << 16);
            *(uint2*)&Ph[n * 72 + rw * 16 + q * 4] = pk;
            if (nt * 64 + f * 16 < NUSE) {   // exclude pad cols (nt14 f2,f3)
                s0 += e0; s1 += e1; s2 += e2; s3 += e3;
            }
        }
        #pragma unroll
        for (int off = 1; off < 16; off <<= 1) {
            s0 += __shfl_xor(s0, off); s1 += __shfl_xor(s1, off);
            s2 += __shfl_xor(s2, off); s3 += __shfl_xor(s3, off);
        }
        if (lm < 4) {
            float sv = (lm == 0) ? s0 : (lm == 1) ? s1 : (lm == 2) ? s2 : s3;
            zslot[(wg * 4 + sl) * 64 + rw * 16 + q * 4 + lm] += sv;   // same lane across v: no race
        }
    }
    __syncthreads();

    // ---- Z + coef ----
    if (tid < 64) {
        int r = tid;
        float im = imp[rc * 64 + r];
        #pragma unroll
        for (int sl = 0; sl < 4; sl++) {
            float Z = zslot[(0 * 4 + sl) * 64 + r] + zslot[(1 * 4 + sl) * 64 + r]
                    + zslot[(2 * 4 + sl) * 64 + r] + zslot[(3 * 4 + sl) * 64 + r];
            coefL[r * 4 + sl] = im / Z;
        }
    }
    __syncthreads();

    // ======== phase 2: weighted column reduce ========
    if (tid < NUSE) {
        int n = tid;
        int sl = (n < 512) ? 0 : (n < 768) ? 1 : (n < 896) ? 2 : 3;
        float acc = 0.f;
        #pragma unroll
        for (int rb = 0; rb < 8; rb++) {
            uint4 pk = *(const uint4*)&Ph[n * 72 + rb * 8];
            const unsigned pv[4] = {pk.x, pk.y, pk.z, pk.w};
            #pragma unroll
            for (int u = 0; u < 4; u++) {
                float v0 = __half2float(__ushort_as_half((unsigned short)(pv[u] & 0xFFFF)));
                float v1 = __half2float(__ushort_as_half((unsigned short)(pv[u] >> 16)));
                int row = rb * 8 + u * 2;
                acc = fmaf(coefL[(row + 0) * 4 + sl], v0, acc);
                acc = fmaf(coefL[(row + 1) * 4 + sl], v1, acc);
            }
        }
        wpart[(long long)rc * NPAD + n] = acc;
    }
}

// ---------------- k_out: reduce wpart, ranks, outputs ----------------
__global__ __launch_bounds__(512) void k_out(const float* __restrict__ wpart,
                                             float* __restrict__ out) {
    const int b = blockIdx.x;
    const int tid = threadIdx.x;
    __shared__ float w_s[NUSE];
    __shared__ int   rk[NUSE];

    for (int n = tid; n < NUSE; n += 512) {
        float s = 0.f;
        #pragma unroll 4
        for (int c = 0; c < 32; c++)
            s += wpart[(long long)(b * 32 + c) * NPAD + n];
        w_s[n] = s;
        if (n < 512)      out[3072 + (long long)b * 512 + n] = s;
        else if (n < 768) out[7168 + (long long)b * 256 + (n - 512)] = s;
    }
    __syncthreads();

    for (int n = tid; n < NUSE; n += 512) {
        int lo, hi;
        if (n < 512)      { lo = 0;   hi = 512; }
        else if (n < 768) { lo = 512; hi = 768; }
        else if (n < 896) { lo = 768; hi = 896; }
        else              { lo = 896; hi = NUSE; }
        float wn = w_s[n];
        int r = 0;
        for (int m = lo; m < hi; m++) {
            float wm = w_s[m];
            r += (wm > wn) || ((wm == wn) && (m < n));
        }
        rk[n] = r;
    }
    __syncthreads();

    if (tid < 512) {
        int n = tid;
        if (rk[n] < 64) {
            int pos = 0;
            for (int m = 0; m < n; m++) pos += (rk[m] < 64) ? 1 : 0;
            out[(long long)b * 64 + pos] = (float)n;
        }
    }
    if (tid < 256) {
        int n = 512 + tid;
        if (rk[n] < 32) {
            int pos = 0;
            for (int m = 512; m < n; m++) pos += (rk[m] < 32) ? 1 : 0;
            out[512 + (long long)b * 32 + pos] = (float)tid;
        }
    }
    if (tid < 128) {
        int n = 768 + tid;
        float v = (rk[n] < 16) ? w_s[n] : 0.f;
        out[768 + (long long)b * 128 + tid] = v;
        out[1792 + (long long)b * 128 + tid] = v;
    }
    if (tid < 32) {
        int n = 896 + tid;
        float v = (rk[n] < 3) ? w_s[n] : 0.f;
        out[2816 + (long long)b * 32 + tid] = v;
    }
}

// ---------------- launch ----------------
extern "C" void kernel_launch(void* const* d_in, const int* in_sizes, int n_in,
                              void* d_out, int out_size, void* d_ws, size_t ws_size,
                              hipStream_t stream) {
    const float* x    = (const float*)d_in[0];
    const float* imp  = (const float*)d_in[1];
    const float* W    = (const float*)d_in[2];
    const float* bias = (const float*)d_in[3];
    const float* emb  = (const float*)d_in[4];

    char* ws = (char*)d_ws;
    unsigned short* ebh = (unsigned short*)(ws + OFF_EBH);
    unsigned short* ebl = (unsigned short*)(ws + OFF_EBL);
    unsigned short* wbh = (unsigned short*)(ws + OFF_WBH);
    unsigned short* wbl = (unsigned short*)(ws + OFF_WBL);
    float* wpart        = (float*)(ws + OFF_WP);
    float* out          = (float*)d_out;

    k_prep<<<12, 256, 0, stream>>>(emb, W, ebh, ebl, wbh, wbl);
    k_mega<<<256, 1024, 0, stream>>>(x, bias, wbh, wbl, ebh, ebl, imp, wpart);
    k_out<<<8, 512, 0, stream>>>(wpart, out);
}